// Round 8
// baseline (964.391 us; speedup 1.0000x reference)
//
#include <hip/hip_runtime.h>
#include <hip/hip_bf16.h>
#include <stdint.h>

typedef __attribute__((ext_vector_type(8))) short bf16x8;
typedef __attribute__((ext_vector_type(4))) float f32x4;
typedef __attribute__((ext_vector_type(4))) unsigned short us4;

#define T_TOK 8192
#define DDIM 1024
#define FDIM 4096
#define F2DIM 2048
#define NEXP 8

#define FENCE() asm volatile("" ::: "memory")
#define BAR() do { FENCE(); __builtin_amdgcn_s_barrier(); FENCE(); } while (0)
#define LGKM0() do { asm volatile("s_waitcnt lgkmcnt(0)" ::: "memory"); \
                     __builtin_amdgcn_sched_barrier(0); } while (0)

__device__ __forceinline__ unsigned short f2bf(float f) {
    unsigned u = __float_as_uint(f);
    u += 0x7fffu + ((u >> 16) & 1u);
    return (unsigned short)(u >> 16);
}
__device__ __forceinline__ float bf2f(unsigned short h) {
    return __uint_as_float(((unsigned)h) << 16);
}
__device__ __forceinline__ float gelu_fast(float v) {
    float u = 0.7978845608028654f * v * (1.0f + 0.044715f * v * v);
    float a = fabsf(u);
    float t = __expf(-2.0f * a);
    float th = (1.0f - t) / (1.0f + t);
    th = u < 0.0f ? -th : th;
    return 0.5f * v * (1.0f + th);
}

__device__ __forceinline__ void gl2lds16(const void* g, void* l) {
    __builtin_amdgcn_global_load_lds(
        (const __attribute__((address_space(1))) unsigned int*)(unsigned long long)g,
        (__attribute__((address_space(3))) unsigned int*)(unsigned int)(unsigned long long)l,
        16, 0, 0);
}

// ---------------- router (+ fused f32->bf16 conversion of x) ----------------
__global__ void k_router(const float* __restrict__ x, const float* __restrict__ rw,
                         const float* __restrict__ rb, int* __restrict__ eid,
                         float* __restrict__ ewt, int* __restrict__ cnt,
                         unsigned short* __restrict__ xb) {
    const int wid = threadIdx.x >> 6, lane = threadIdx.x & 63;
    const int t = blockIdx.x * 4 + wid;
    float acc[8];
#pragma unroll
    for (int e = 0; e < 8; ++e) acc[e] = 0.f;
    const float4* xr = (const float4*)(x + (long long)t * DDIM);
#pragma unroll
    for (int c = 0; c < 4; ++c) {
        float4 xv = xr[lane + 64 * c];
        int d0 = (lane + 64 * c) * 4;
        us4 o;
        o.x = f2bf(xv.x); o.y = f2bf(xv.y); o.z = f2bf(xv.z); o.w = f2bf(xv.w);
        *(us4*)(xb + (long long)t * DDIM + d0) = o;
        float xs[4] = {xv.x, xv.y, xv.z, xv.w};
#pragma unroll
        for (int j = 0; j < 4; ++j) {
            const float* wrow = rw + (long long)(d0 + j) * 8;
#pragma unroll
            for (int e = 0; e < 8; ++e) acc[e] += xs[j] * wrow[e];
        }
    }
#pragma unroll
    for (int off = 32; off; off >>= 1)
#pragma unroll
        for (int e = 0; e < 8; ++e) acc[e] += __shfl_xor(acc[e], off);
    if (lane == 0) {
        float lg[8];
#pragma unroll
        for (int e = 0; e < 8; ++e) lg[e] = acc[e] + rb[e];
        int e0 = 0;
#pragma unroll
        for (int e = 1; e < 8; ++e) if (lg[e] > lg[e0]) e0 = e;
        int e1 = -1;
#pragma unroll
        for (int e = 0; e < 8; ++e) {
            if (e == e0) continue;
            if (e1 < 0 || lg[e] > lg[e1]) e1 = e;
        }
        float w0 = 1.f / (1.f + expf(lg[e1] - lg[e0]));
        eid[2 * t] = e0; eid[2 * t + 1] = e1;
        ewt[2 * t] = w0; ewt[2 * t + 1] = 1.f - w0;
        atomicAdd(&cnt[e0], 1);
        atomicAdd(&cnt[e1], 1);
    }
}

__global__ void k_scan(const int* __restrict__ cnt, int* __restrict__ offs,
                       int* __restrict__ cursor) {
    if (threadIdx.x == 0) {
        int s = 0;
        for (int e = 0; e < NEXP; ++e) { offs[e] = s; cursor[e] = s; s += cnt[e]; }
        offs[NEXP] = s;
    }
}

__global__ void k_scatter(const int* __restrict__ eid, const float* __restrict__ ewt,
                          int* __restrict__ cursor, int* __restrict__ rowtok,
                          float* __restrict__ roww, int* __restrict__ pos) {
    int t = blockIdx.x * blockDim.x + threadIdx.x;
#pragma unroll
    for (int k = 0; k < 2; ++k) {
        int e = eid[2 * t + k];
        int p = atomicAdd(&cursor[e], 1);
        rowtok[p] = (t << 1) | k;
        roww[p] = ewt[2 * t + k];
        pos[2 * t + k] = p;
    }
}

// ------- all 4 weight transposes in ONE launch: [R][C] f32 -> [C][R] bf16 -----
__global__ void k_tpAll(const float* __restrict__ w1, const float* __restrict__ w2,
                        const float* __restrict__ sw1, const float* __restrict__ sw2,
                        unsigned short* __restrict__ w1t, unsigned short* __restrict__ w2t,
                        unsigned short* __restrict__ sw1t, unsigned short* __restrict__ sw2t) {
    int t = blockIdx.x;
    const float* in; unsigned short* out; int R, C; long long base; int c0, r0;
    if (t < 16384) {
        int e = t >> 11, l = t & 2047;
        in = w1; out = w1t; R = 1024; C = 4096; base = (long long)e * R * C;
        c0 = (l & 127) * 32; r0 = (l >> 7) * 64;
    } else if (t < 32768) {
        int tt = t - 16384; int e = tt >> 11, l = tt & 2047;
        in = w2; out = w2t; R = 4096; C = 1024; base = (long long)e * R * C;
        c0 = (l & 31) * 32; r0 = (l >> 5) * 64;
    } else if (t < 33792) {
        int l = t - 32768;
        in = sw1; out = sw1t; R = 1024; C = 2048; base = 0;
        c0 = (l & 63) * 32; r0 = (l >> 6) * 64;
    } else {
        int l = t - 33792;
        in = sw2; out = sw2t; R = 2048; C = 1024; base = 0;
        c0 = (l & 31) * 32; r0 = (l >> 5) * 64;
    }
    __shared__ unsigned short ts[32][80];
    const int tid = threadIdx.x;
#pragma unroll
    for (int i = 0; i < 2; ++i) {
        int idx = tid + i * 256;
        int row = idx >> 3, c4 = idx & 7;
        float4 v = *(const float4*)(in + base + (long long)(r0 + row) * C + c0 + c4 * 4);
        ts[c4 * 4 + 0][row] = f2bf(v.x);
        ts[c4 * 4 + 1][row] = f2bf(v.y);
        ts[c4 * 4 + 2][row] = f2bf(v.z);
        ts[c4 * 4 + 3][row] = f2bf(v.w);
    }
    __syncthreads();
    int c = tid >> 3, r8 = tid & 7;
    uint4 o = *(const uint4*)&ts[c][r8 * 8];
    *(uint4*)(out + base + (long long)(c0 + c) * R + r0 + r8 * 8) = o;
}

// ============ grouped GEMM: 8-phase counted-vmcnt template (m201/m248 port) ====
// Tile 256 x BN (BN=256 fc1 / 128 fc2), BK=64 as two K-halves; 512 thr = 8 waves
// (2M x 4N), wave tile 128 x BN/4. LDS [2buf][2kh][rows][32] bf16, each unit
// contiguous 16KB(A)/BN*64B(B) for linear global_load_lds; 16B-chunk swizzle
// slot = kc ^ (row&3) ^ ((row>>2)&1) applied source-side and read-side.
// Per K-tile, 4 phases (kk,mh): {ds_read frags; stage 1 unit; [vmcnt@ph3];
// BAR; lgkm0+schedbar; setprio1; 4*NB MFMA; setprio0; BAR}.
// Stage schedule: ph0:A(t+1,kh1) ph1:B(t+1,kh1) ph2:A(t+2,kh0) ph3:B(t+2,kh0).
// Race-safe: t+2.kh0 overwrites buf[t&1] kh0, read only by ph0/ph1 (barrier-
// retired). Ledger: vmcnt(2+LB) at ph3 proves tile t+1 fully landed.
template <int FC>
__launch_bounds__(512, 2)
__global__ void k_fc8(const short* __restrict__ Amoe, const short* __restrict__ Ash,
                      const short* __restrict__ Bmoe, const short* __restrict__ Bsh,
                      const float* __restrict__ biasM, const float* __restrict__ biasS,
                      const float* __restrict__ gateM, const float* __restrict__ gateS,
                      unsigned short* __restrict__ outM, unsigned short* __restrict__ outS,
                      const int* __restrict__ cnt, const int* __restrict__ offs,
                      const int* __restrict__ rowtok, const float* __restrict__ roww,
                      const float* __restrict__ swp) {
    constexpr int BN = (FC == 1) ? 256 : 128;
    constexpr int NB = BN / 64;          // n-frags per wave
    constexpr int LB = BN / 128;         // B loads per thread per unit

    // ---- tile decode: (z, cb, rb), rb fastest, XCD-bijective swizzle ----
    int RBz[9];
    int T = 0;
#pragma unroll
    for (int zz = 0; zz < 9; ++zz) {
        int Mz = (zz < 8) ? cnt[zz] : T_TOK;
        int rbn = (Mz + 255) >> 8;
        int cbn = (FC == 1) ? ((zz < 8) ? 16 : 8) : 8;
        RBz[zz] = rbn;
        T += rbn * cbn;
    }
    const int ell = blockIdx.x;
    if (ell >= T) return;
    const int q = T >> 3, r = T & 7;
    const int xk = ell & 7, jj = ell >> 3;
    int t0 = (xk < r ? xk * (q + 1) : r * (q + 1) + (xk - r) * q) + jj;

    int z = 0, local = t0;
    for (; z < 9; ++z) {
        int cbn = (FC == 1) ? ((z < 8) ? 16 : 8) : 8;
        int tz = RBz[z] * cbn;
        if (local < tz) break;
        local -= tz;
    }
    const int RB = RBz[z];
    const int cb = local / RB;
    const int rb = local - cb * RB;

    const bool sh = (z == 8);
    const int Kd = (FC == 1) ? 1024 : (sh ? 2048 : 4096);
    const int Ncols = (FC == 1) ? (sh ? 2048 : 4096) : 1024;
    const int M = sh ? T_TOK : cnt[z];
    const int oE = sh ? 0 : offs[z];

    const short* A = sh ? Ash : Amoe;
    const short* B = sh ? Bsh
                        : Bmoe + (long long)z * ((FC == 1) ? (long long)FDIM * DDIM
                                                           : (long long)DDIM * FDIM);

    extern __shared__ short smem[];
    // A units: ((buf<<1)|kh)*8192 shorts (16KB). B region at 32768 shorts.
    constexpr int BOFF = 32768;
    constexpr int BUNIT = BN * 32;       // shorts per B unit

    const int tid = threadIdx.x, w = tid >> 6, lane = tid & 63;
    const int fr = lane & 15, fg = lane >> 4;
    const int wr = w >> 2, wc = w & 3;

    // ---- staging pointers: thread handles chunk rows (tid>>2) and 128+(tid>>2)
    const int srow = tid >> 2;
    const int kc = (tid & 3) ^ (srow & 3) ^ ((srow >> 2) & 1);
    const short *ap1, *ap2, *bp1, *bp2;
    {
        int r1 = rb * 256 + srow; if (r1 > M - 1) r1 = M - 1;
        int r2 = rb * 256 + 128 + srow; if (r2 > M - 1) r2 = M - 1;
        long long x1, x2;
        if (sh) { x1 = r1; x2 = r2; }
        else if (FC == 1) { x1 = rowtok[oE + r1] >> 1; x2 = rowtok[oE + r2] >> 1; }
        else { x1 = oE + r1; x2 = oE + r2; }
        ap1 = A + x1 * (long long)Kd + kc * 8;
        ap2 = A + x2 * (long long)Kd + kc * 8;
        bp1 = B + (long long)(cb * BN + srow) * Kd + kc * 8;
        bp2 = B + (long long)(cb * BN + ((BN == 256) ? 128 + srow : srow)) * Kd + kc * 8;
    }
    const int wofs = w * 512;            // shorts, wave-uniform LDS chunk base

    f32x4 acc[8][NB];
#pragma unroll
    for (int m = 0; m < 8; ++m)
#pragma unroll
        for (int n = 0; n < NB; ++n)
            acc[m][n] = (f32x4){0.f, 0.f, 0.f, 0.f};

    // read-side swizzled thread offsets (shorts)
    const int slot = fg ^ (fr & 3) ^ ((fr >> 2) & 1);
    const int athr = (wr * 128 + fr) * 32 + slot * 8;
    const int bthr = (wc * (BN / 4) + fr) * 32 + slot * 8;
    const int nt = Kd / 64;

#define STG_A(khv, bufv, koff) do { \
    int u_ = (((bufv) << 1) | (khv)) * 8192; \
    gl2lds16(ap1 + (koff), smem + u_ + wofs); \
    gl2lds16(ap2 + (koff), smem + u_ + 4096 + wofs); } while (0)
#define STG_B(khv, bufv, koff) do { \
    int u_ = BOFF + (((bufv) << 1) | (khv)) * BUNIT; \
    gl2lds16(bp1 + (koff), smem + u_ + wofs); \
    if (BN == 256) gl2lds16(bp2 + (koff), smem + u_ + 4096 + wofs); } while (0)

    // prologue: tile0 all units + tile1 kh0; verify tile0 landed (2+LB in flight)
    STG_A(0, 0, 0);  STG_B(0, 0, 0);
    STG_A(1, 0, 32); STG_B(1, 0, 32);
    STG_A(0, 1, 64); STG_B(0, 1, 64);
    if (FC == 1) asm volatile("s_waitcnt vmcnt(4)" ::: "memory");
    else         asm volatile("s_waitcnt vmcnt(3)" ::: "memory");
    BAR();

    for (int t = 0; t < nt; ++t) {
        const int buf = t & 1;
        const bool s1 = (t + 1 < nt), s2 = (t + 2 < nt);
        const int ua0 = (buf << 1) * 8192;          // A unit kk0
        const int ua1 = ((buf << 1) | 1) * 8192;    // A unit kk1
        const int ub0 = BOFF + (buf << 1) * BUNIT;
        const int ub1 = BOFF + ((buf << 1) | 1) * BUNIT;
        bf16x8 a[4], b[NB];

        // ---- ph0: kk0, mh0 ----
#pragma unroll
        for (int mi = 0; mi < 4; ++mi)
            a[mi] = *(const bf16x8*)(smem + ua0 + athr + mi * 512);
#pragma unroll
        for (int n = 0; n < NB; ++n)
            b[n] = *(const bf16x8*)(smem + ub0 + bthr + n * 512);
        if (s1) STG_A(1, buf ^ 1, 96);
        BAR(); LGKM0();
        __builtin_amdgcn_s_setprio(1);
#pragma unroll
        for (int mi = 0; mi < 4; ++mi)
#pragma unroll
            for (int n = 0; n < NB; ++n)
                acc[mi][n] = __builtin_amdgcn_mfma_f32_16x16x32_bf16(a[mi], b[n], acc[mi][n], 0, 0, 0);
        __builtin_amdgcn_s_setprio(0);
        BAR();

        // ---- ph1: kk0, mh1 ----
#pragma unroll
        for (int mi = 0; mi < 4; ++mi)
            a[mi] = *(const bf16x8*)(smem + ua0 + athr + (mi + 4) * 512);
        if (s1) STG_B(1, buf ^ 1, 96);
        BAR(); LGKM0();
        __builtin_amdgcn_s_setprio(1);
#pragma unroll
        for (int mi = 0; mi < 4; ++mi)
#pragma unroll
            for (int n = 0; n < NB; ++n)
                acc[mi + 4][n] = __builtin_amdgcn_mfma_f32_16x16x32_bf16(a[mi], b[n], acc[mi + 4][n], 0, 0, 0);
        __builtin_amdgcn_s_setprio(0);
        BAR();

        // ---- ph2: kk1, mh0 ----
#pragma unroll
        for (int mi = 0; mi < 4; ++mi)
            a[mi] = *(const bf16x8*)(smem + ua1 + athr + mi * 512);
#pragma unroll
        for (int n = 0; n < NB; ++n)
            b[n] = *(const bf16x8*)(smem + ub1 + bthr + n * 512);
        if (s2) STG_A(0, buf, 128);
        BAR(); LGKM0();
        __builtin_amdgcn_s_setprio(1);
#pragma unroll
        for (int mi = 0; mi < 4; ++mi)
#pragma unroll
            for (int n = 0; n < NB; ++n)
                acc[mi][n] = __builtin_amdgcn_mfma_f32_16x16x32_bf16(a[mi], b[n], acc[mi][n], 0, 0, 0);
        __builtin_amdgcn_s_setprio(0);
        BAR();

        // ---- ph3: kk1, mh1 ----
#pragma unroll
        for (int mi = 0; mi < 4; ++mi)
            a[mi] = *(const bf16x8*)(smem + ua1 + athr + (mi + 4) * 512);
        if (s2) {
            STG_B(0, buf, 128);
            if (FC == 1) asm volatile("s_waitcnt vmcnt(4)" ::: "memory");
            else         asm volatile("s_waitcnt vmcnt(3)" ::: "memory");
        } else if (s1) {
            asm volatile("s_waitcnt vmcnt(0)" ::: "memory");
        }
        BAR(); LGKM0();
        __builtin_amdgcn_s_setprio(1);
#pragma unroll
        for (int mi = 0; mi < 4; ++mi)
#pragma unroll
            for (int n = 0; n < NB; ++n)
                acc[mi + 4][n] = __builtin_amdgcn_mfma_f32_16x16x32_bf16(a[mi], b[n], acc[mi + 4][n], 0, 0, 0);
        __builtin_amdgcn_s_setprio(0);
        BAR();

        ap1 += 64; ap2 += 64; bp1 += 64;
        if (BN == 256) bp2 += 64;
    }
#undef STG_A
#undef STG_B

    // ---- epilogue. C/D: col=lane&15, row=(lane>>4)*4+i. ----
    const int mrow0 = rb * 256 + wr * 128;
    const int col0 = cb * BN + wc * (BN / 4);

    if (FC == 1) {
        const float* bp = sh ? biasS : biasM + (long long)z * FDIM;
        const float* gp = sh ? gateS : gateM + (long long)z * FDIM;
        unsigned short* outp = sh ? outS : outM;
        const long long obase = sh ? 0 : (long long)oE;
        float bv[NB], gv[NB]; int coln[NB];
#pragma unroll
        for (int n = 0; n < NB; ++n) {
            coln[n] = col0 + n * 16 + fr;
            bv[n] = bp[coln[n]];
            gv[n] = gp[coln[n]];
        }
#pragma unroll
        for (int m = 0; m < 8; ++m) {
#pragma unroll
            for (int i = 0; i < 4; ++i) {
                int grow = mrow0 + m * 16 + fg * 4 + i;
                if (grow < M) {
                    unsigned short* rowp = outp + (obase + grow) * (long long)Ncols;
#pragma unroll
                    for (int n = 0; n < NB; ++n) {
                        float v = (acc[m][n][i] + bv[n]) * gv[n];
                        rowp[coln[n]] = f2bf(gelu_fast(v));
                    }
                }
            }
        }
    } else {
        float bv[NB]; int coln[NB];
        const float* bp = sh ? biasS : biasM + (long long)z * DDIM;
#pragma unroll
        for (int n = 0; n < NB; ++n) {
            coln[n] = col0 + n * 16 + fr;
            bv[n] = bp[coln[n]];
        }
        if (sh) {
            float sigw = 1.f / (1.f + expf(-swp[0]));
#pragma unroll
            for (int m = 0; m < 8; ++m) {
#pragma unroll
                for (int i = 0; i < 4; ++i) {
                    int grow = mrow0 + m * 16 + fg * 4 + i;
                    if (grow < M) {
                        unsigned short* rowp = outS + (long long)grow * DDIM;
#pragma unroll
                        for (int n = 0; n < NB; ++n)
                            rowp[coln[n]] = f2bf((acc[m][n][i] + bv[n]) * sigw);
                    }
                }
            }
        } else {
#pragma unroll
            for (int m = 0; m < 8; ++m) {
#pragma unroll
                for (int i = 0; i < 4; ++i) {
                    int grow = mrow0 + m * 16 + fg * 4 + i;
                    if (grow < M) {
                        int p = oE + grow;
                        float wv = roww[p];
                        unsigned short* rowp = outM + (long long)p * DDIM;   // compact
#pragma unroll
                        for (int n = 0; n < NB; ++n)
                            rowp[coln[n]] = f2bf((acc[m][n][i] + bv[n]) * wv);
                    }
                }
            }
        }
    }
}

// ------- final: y = ycomp[pos0]+ycomp[pos1]+ysh ; LayerNorm over D -------
__global__ void k_ln(const unsigned short* __restrict__ yc,
                     const unsigned short* __restrict__ ysh,
                     const int* __restrict__ pos,
                     const float* __restrict__ g, const float* __restrict__ b,
                     float* __restrict__ out) {
    const int wid = threadIdx.x >> 6, lane = threadIdx.x & 63;
    const long long t = (long long)blockIdx.x * 4 + wid;
    const long long b0 = (long long)pos[2 * t] * DDIM;
    const long long b1 = (long long)pos[2 * t + 1] * DDIM;
    const long long bs = t * DDIM;
    float v[16];
    float s = 0.f, sq = 0.f;
#pragma unroll
    for (int j = 0; j < 2; ++j) {
        int c0 = (lane + 64 * j) * 8;
        uint4 a0 = *(const uint4*)(yc + b0 + c0);
        uint4 a1 = *(const uint4*)(yc + b1 + c0);
        uint4 a2 = *(const uint4*)(ysh + bs + c0);
        const unsigned* u0 = (const unsigned*)&a0;
        const unsigned* u1 = (const unsigned*)&a1;
        const unsigned* u2 = (const unsigned*)&a2;
#pragma unroll
        for (int qq = 0; qq < 4; ++qq) {
            float lo = bf2f((unsigned short)u0[qq]) + bf2f((unsigned short)u1[qq]) +
                       bf2f((unsigned short)u2[qq]);
            float hi = bf2f((unsigned short)(u0[qq] >> 16)) + bf2f((unsigned short)(u1[qq] >> 16)) +
                       bf2f((unsigned short)(u2[qq] >> 16));
            v[j * 8 + qq * 2] = lo;
            v[j * 8 + qq * 2 + 1] = hi;
            s += lo + hi;
            sq += lo * lo + hi * hi;
        }
    }
#pragma unroll
    for (int off = 32; off; off >>= 1) {
        s += __shfl_xor(s, off);
        sq += __shfl_xor(sq, off);
    }
    const float mean = s * (1.f / DDIM);
    const float var = sq * (1.f / DDIM) - mean * mean;
    const float inv = rsqrtf(var + 1e-5f);
#pragma unroll
    for (int j = 0; j < 2; ++j) {
        int c0 = (lane + 64 * j) * 8;
#pragma unroll
        for (int h = 0; h < 2; ++h) {
            float4 o4;
            float* op = (float*)&o4;
#pragma unroll
            for (int qq = 0; qq < 4; ++qq) {
                int k = h * 4 + qq;
                int col = c0 + k;
                op[qq] = (v[j * 8 + k] - mean) * inv * g[col] + b[col];
            }
            *(float4*)(out + bs + c0 + h * 4) = o4;
        }
    }
}

extern "C" void kernel_launch(void* const* d_in, const int* in_sizes, int n_in,
                              void* d_out, int out_size, void* d_ws, size_t ws_size,
                              hipStream_t stream) {
    const float* x    = (const float*)d_in[0];
    const float* rw   = (const float*)d_in[1];
    const float* rb   = (const float*)d_in[2];
    const float* w1   = (const float*)d_in[3];
    const float* b1   = (const float*)d_in[4];
    const float* gate = (const float*)d_in[5];
    const float* w2   = (const float*)d_in[6];
    const float* b2   = (const float*)d_in[7];
    const float* sw1  = (const float*)d_in[8];
    const float* sb1  = (const float*)d_in[9];
    const float* sgate= (const float*)d_in[10];
    const float* sw2  = (const float*)d_in[11];
    const float* sb2  = (const float*)d_in[12];
    const float* swt  = (const float*)d_in[13];
    const float* lng  = (const float*)d_in[14];
    const float* lnb  = (const float*)d_in[15];
    float* out = (float*)d_out;

    char* p = (char*)d_ws;
    auto take = [&](size_t n) { char* r = p; p += (n + 255) & ~(size_t)255; return r; };
    short* xb   = (short*)take((size_t)T_TOK * DDIM * 2);
    short* w1t  = (short*)take((size_t)NEXP * FDIM * DDIM * 2);
    short* w2t  = (short*)take((size_t)NEXP * DDIM * FDIM * 2);
    short* sw1t = (short*)take((size_t)F2DIM * DDIM * 2);
    short* sw2t = (short*)take((size_t)DDIM * F2DIM * 2);
    short* hbuf = (short*)take((size_t)2 * T_TOK * FDIM * 2);
    short* hs   = (short*)take((size_t)T_TOK * F2DIM * 2);
    unsigned short* ycomp = (unsigned short*)take((size_t)2 * T_TOK * DDIM * 2);
    unsigned short* ysh   = (unsigned short*)take((size_t)T_TOK * DDIM * 2);
    int* eid    = (int*)take((size_t)T_TOK * 2 * 4);
    float* ewt  = (float*)take((size_t)T_TOK * 2 * 4);
    int* rowtok = (int*)take((size_t)2 * T_TOK * 4);
    float* roww = (float*)take((size_t)2 * T_TOK * 4);
    int* pos    = (int*)take((size_t)2 * T_TOK * 4);
    int* cnt    = (int*)take(64);
    int* offs   = (int*)take(64);
    int* cursor = (int*)take(64);

    hipFuncSetAttribute(reinterpret_cast<const void*>(k_fc8<1>),
                        hipFuncAttributeMaxDynamicSharedMemorySize, 131072);
    hipFuncSetAttribute(reinterpret_cast<const void*>(k_fc8<2>),
                        hipFuncAttributeMaxDynamicSharedMemorySize, 98304);

    hipMemsetAsync(cnt, 0, NEXP * sizeof(int), stream);
    k_router<<<T_TOK / 4, 256, 0, stream>>>(x, rw, rb, eid, ewt, cnt, (unsigned short*)xb);
    k_scan<<<1, 64, 0, stream>>>(cnt, offs, cursor);
    k_scatter<<<T_TOK / 256, 256, 0, stream>>>(eid, ewt, cursor, rowtok, roww, pos);

    k_tpAll<<<34816, 256, 0, stream>>>(w1, w2, sw1, sw2,
                                       (unsigned short*)w1t, (unsigned short*)w2t,
                                       (unsigned short*)sw1t, (unsigned short*)sw2t);

    // fc1: T <= 72*16 + 32*8 = 1408 (extra blocks exit on ell>=T)
    k_fc8<1><<<1408, 512, 131072, stream>>>(
        xb, xb, w1t, sw1t, b1, sb1, gate, sgate,
        (unsigned short*)hbuf, (unsigned short*)hs, cnt, offs, rowtok, roww, swt);
    // fc2: T <= 72*8 + 32*8 = 832
    k_fc8<2><<<832, 512, 98304, stream>>>(
        hbuf, hs, w2t, sw2t, b2, sb2, (const float*)nullptr, (const float*)nullptr,
        ycomp, ysh, cnt, offs, rowtok, roww, swt);

    k_ln<<<T_TOK / 4, 256, 0, stream>>>(ycomp, ysh, pos, lng, lnb, out);
}

// Round 9
// 838.155 us; speedup vs baseline: 1.1506x; 1.1506x over previous
//
#include <hip/hip_runtime.h>
#include <hip/hip_bf16.h>
#include <stdint.h>

typedef __attribute__((ext_vector_type(8))) short bf16x8;
typedef __attribute__((ext_vector_type(4))) float f32x4;
typedef __attribute__((ext_vector_type(4))) unsigned short us4;

#define T_TOK 8192
#define DDIM 1024
#define FDIM 4096
#define F2DIM 2048
#define NEXP 8

__device__ __forceinline__ unsigned short f2bf(float f) {
    unsigned u = __float_as_uint(f);
    u += 0x7fffu + ((u >> 16) & 1u);
    return (unsigned short)(u >> 16);
}
__device__ __forceinline__ float bf2f(unsigned short h) {
    return __uint_as_float(((unsigned)h) << 16);
}
__device__ __forceinline__ float gelu_fast(float v) {
    float u = 0.7978845608028654f * v * (1.0f + 0.044715f * v * v);
    float a = fabsf(u);
    float t = __expf(-2.0f * a);
    float th = (1.0f - t) / (1.0f + t);
    th = u < 0.0f ? -th : th;
    return 0.5f * v * (1.0f + th);
}

// async global->LDS, 16B per lane. LDS dest is wave-uniform base + lane*16.
__device__ __forceinline__ void gl2lds16(const void* g, void* l) {
    __builtin_amdgcn_global_load_lds(
        (const __attribute__((address_space(1))) unsigned int*)(unsigned long long)g,
        (__attribute__((address_space(3))) unsigned int*)(unsigned int)(unsigned long long)l,
        16, 0, 0);
}

// ---------------- router (+ fused f32->bf16 conversion of x) ----------------
__global__ void k_router(const float* __restrict__ x, const float* __restrict__ rw,
                         const float* __restrict__ rb, int* __restrict__ eid,
                         float* __restrict__ ewt, int* __restrict__ cnt,
                         unsigned short* __restrict__ xb) {
    const int wid = threadIdx.x >> 6, lane = threadIdx.x & 63;
    const int t = blockIdx.x * 4 + wid;
    float acc[8];
#pragma unroll
    for (int e = 0; e < 8; ++e) acc[e] = 0.f;
    const float4* xr = (const float4*)(x + (long long)t * DDIM);
#pragma unroll
    for (int c = 0; c < 4; ++c) {
        float4 xv = xr[lane + 64 * c];
        int d0 = (lane + 64 * c) * 4;
        us4 o;
        o.x = f2bf(xv.x); o.y = f2bf(xv.y); o.z = f2bf(xv.z); o.w = f2bf(xv.w);
        *(us4*)(xb + (long long)t * DDIM + d0) = o;
        float xs[4] = {xv.x, xv.y, xv.z, xv.w};
#pragma unroll
        for (int j = 0; j < 4; ++j) {
            const float* wrow = rw + (long long)(d0 + j) * 8;
#pragma unroll
            for (int e = 0; e < 8; ++e) acc[e] += xs[j] * wrow[e];
        }
    }
#pragma unroll
    for (int off = 32; off; off >>= 1)
#pragma unroll
        for (int e = 0; e < 8; ++e) acc[e] += __shfl_xor(acc[e], off);
    if (lane == 0) {
        float lg[8];
#pragma unroll
        for (int e = 0; e < 8; ++e) lg[e] = acc[e] + rb[e];
        int e0 = 0;
#pragma unroll
        for (int e = 1; e < 8; ++e) if (lg[e] > lg[e0]) e0 = e;
        int e1 = -1;
#pragma unroll
        for (int e = 0; e < 8; ++e) {
            if (e == e0) continue;
            if (e1 < 0 || lg[e] > lg[e1]) e1 = e;
        }
        float w0 = 1.f / (1.f + expf(lg[e1] - lg[e0]));
        eid[2 * t] = e0; eid[2 * t + 1] = e1;
        ewt[2 * t] = w0; ewt[2 * t + 1] = 1.f - w0;
        atomicAdd(&cnt[e0], 1);
        atomicAdd(&cnt[e1], 1);
    }
}

__global__ void k_scan(const int* __restrict__ cnt, int* __restrict__ offs,
                       int* __restrict__ cursor) {
    if (threadIdx.x == 0) {
        int s = 0;
        for (int e = 0; e < NEXP; ++e) { offs[e] = s; cursor[e] = s; s += cnt[e]; }
        offs[NEXP] = s;
    }
}

__global__ void k_scatter(const int* __restrict__ eid, const float* __restrict__ ewt,
                          int* __restrict__ cursor, int* __restrict__ rowtok,
                          float* __restrict__ roww, int* __restrict__ pos) {
    int t = blockIdx.x * blockDim.x + threadIdx.x;
#pragma unroll
    for (int k = 0; k < 2; ++k) {
        int e = eid[2 * t + k];
        int p = atomicAdd(&cursor[e], 1);
        rowtok[p] = (t << 1) | k;
        roww[p] = ewt[2 * t + k];
        pos[2 * t + k] = p;
    }
}

// ------- all 4 weight transposes in ONE launch: [R][C] f32 -> [C][R] bf16 -----
__global__ void k_tpAll(const float* __restrict__ w1, const float* __restrict__ w2,
                        const float* __restrict__ sw1, const float* __restrict__ sw2,
                        unsigned short* __restrict__ w1t, unsigned short* __restrict__ w2t,
                        unsigned short* __restrict__ sw1t, unsigned short* __restrict__ sw2t) {
    int t = blockIdx.x;
    const float* in; unsigned short* out; int R, C; long long base; int c0, r0;
    if (t < 16384) {
        int e = t >> 11, l = t & 2047;
        in = w1; out = w1t; R = 1024; C = 4096; base = (long long)e * R * C;
        c0 = (l & 127) * 32; r0 = (l >> 7) * 64;
    } else if (t < 32768) {
        int tt = t - 16384; int e = tt >> 11, l = tt & 2047;
        in = w2; out = w2t; R = 4096; C = 1024; base = (long long)e * R * C;
        c0 = (l & 31) * 32; r0 = (l >> 5) * 64;
    } else if (t < 33792) {
        int l = t - 32768;
        in = sw1; out = sw1t; R = 1024; C = 2048; base = 0;
        c0 = (l & 63) * 32; r0 = (l >> 6) * 64;
    } else {
        int l = t - 33792;
        in = sw2; out = sw2t; R = 2048; C = 1024; base = 0;
        c0 = (l & 31) * 32; r0 = (l >> 5) * 64;
    }
    __shared__ unsigned short ts[32][80];
    const int tid = threadIdx.x;
#pragma unroll
    for (int i = 0; i < 2; ++i) {
        int idx = tid + i * 256;
        int row = idx >> 3, c4 = idx & 7;
        float4 v = *(const float4*)(in + base + (long long)(r0 + row) * C + c0 + c4 * 4);
        ts[c4 * 4 + 0][row] = f2bf(v.x);
        ts[c4 * 4 + 1][row] = f2bf(v.y);
        ts[c4 * 4 + 2][row] = f2bf(v.z);
        ts[c4 * 4 + 3][row] = f2bf(v.w);
    }
    __syncthreads();
    int c = tid >> 3, r8 = tid & 7;
    uint4 o = *(const uint4*)&ts[c][r8 * 8];
    *(uint4*)(out + base + (long long)(c0 + c) * R + r0 + r8 * 8) = o;
}

// ---- grouped GEMM: 128x128 tile, BK=64 as two proven 32-k sub-units ----------
// 4 waves (2Mx2N), wave tile 64x64, single-buffered 32KB LDS.
// Each 32-k sub-unit is byte-identical to the R6 unit: [128 rows][4 chunks of
// 16B], source pre-swizzle gc = c ^ ((row>>1)&3), read slot = fg ^ ((fr>>1)&3)
// (measured 0 bank conflicts). Per K-step: 8 gl2lds -> sync -> 2 x {8
// ds_read_b128 + 16 MFMA} -> sync. Steps per tile halved vs BK=32.
// fc1 tile order (z, cb, rb) rb-fastest (B-panel L2 locality);
// fc2 cb-fastest (A-tile L2 locality). Bijective XCD chunk swizzle (m204).
template <int FC>
__launch_bounds__(256, 4)
__global__ void k_fc(const short* __restrict__ Amoe, const short* __restrict__ Ash,
                     const short* __restrict__ Bmoe, const short* __restrict__ Bsh,
                     const float* __restrict__ biasM, const float* __restrict__ biasS,
                     const float* __restrict__ gateM, const float* __restrict__ gateS,
                     unsigned short* __restrict__ outM, unsigned short* __restrict__ outS,
                     const int* __restrict__ cnt, const int* __restrict__ offs,
                     const int* __restrict__ rowtok, const float* __restrict__ roww,
                     const float* __restrict__ swp) {
    // ---- tile decode ----
    int RBz[9];
    int T = 0;
#pragma unroll
    for (int zz = 0; zz < 9; ++zz) {
        int Mz = (zz < 8) ? cnt[zz] : T_TOK;
        int rbn = (Mz + 127) >> 7;
        int cbn = (FC == 1) ? ((zz < 8) ? 32 : 16) : 8;
        RBz[zz] = rbn;
        T += rbn * cbn;
    }
    const int ell = blockIdx.x;
    if (ell >= T) return;
    const int q = T >> 3, r = T & 7;
    const int xk = ell & 7, jj = ell >> 3;
    int t = (xk < r ? xk * (q + 1) : r * (q + 1) + (xk - r) * q) + jj;

    int z = 0, local = t;
    for (; z < 9; ++z) {
        int cbn = (FC == 1) ? ((z < 8) ? 32 : 16) : 8;
        int tz = RBz[z] * cbn;
        if (local < tz) break;
        local -= tz;
    }
    const int RB = RBz[z];
    int cb, rb;
    if (FC == 1) {                 // rb fastest: B-panel reuse
        cb = local / RB;
        rb = local - cb * RB;
    } else {                       // cb fastest: A-tile reuse
        rb = local >> 3;           // CBN = 8
        cb = local & 7;
    }

    const bool sh = (z == 8);
    const int Kd = (FC == 1) ? 1024 : (sh ? 2048 : 4096);
    const int Ncols = (FC == 1) ? (sh ? 2048 : 4096) : 1024;
    const int M = sh ? T_TOK : cnt[z];
    const int oE = sh ? 0 : offs[z];

    const short* A = sh ? Ash : Amoe;
    const short* B = sh ? Bsh
                        : Bmoe + (long long)z * ((FC == 1) ? (long long)FDIM * DDIM
                                                           : (long long)DDIM * FDIM);

    __shared__ short As[2][4096];   // two 32-k sub-units, 8KB each
    __shared__ short Bs[2][4096];

    const int tid = threadIdx.x, w = tid >> 6, lane = tid & 63;
    const int fr = lane & 15, fg = lane >> 4;
    const int wr = w >> 1, wc = w & 1;

    // staging: per sub-unit 512 chunks of 16B; chunk id in {tid, tid+256}:
    // row = id>>2, c = id&3, source chunk gc = c ^ ((row>>1)&3); LDS linear.
    const short *ag0, *ag1, *bg0, *bg1;
    {
        int id = tid, row = id >> 2;
        int gc = (id & 3) ^ ((row >> 1) & 3);
        int rA = rb * 128 + row; if (rA > M - 1) rA = M - 1;
        long long rowix;
        if (FC == 1) rowix = sh ? (long long)rA : (long long)(rowtok[oE + rA] >> 1);
        else         rowix = sh ? (long long)rA : (long long)(oE + rA);
        ag0 = A + rowix * (long long)Kd + gc * 8;
        bg0 = B + (long long)(cb * 128 + row) * Kd + gc * 8;
    }
    {
        int id = tid + 256, row = id >> 2;
        int gc = (id & 3) ^ ((row >> 1) & 3);
        int rA = rb * 128 + row; if (rA > M - 1) rA = M - 1;
        long long rowix;
        if (FC == 1) rowix = sh ? (long long)rA : (long long)(rowtok[oE + rA] >> 1);
        else         rowix = sh ? (long long)rA : (long long)(oE + rA);
        ag1 = A + rowix * (long long)Kd + gc * 8;
        bg1 = B + (long long)(cb * 128 + row) * Kd + gc * 8;
    }
    // wave-uniform LDS dest bases (HW adds lane*16B); offsets in shorts
    short* const a0d0 = &As[0][0] + w * 512;
    short* const a0d1 = &As[0][0] + 2048 + w * 512;
    short* const a1d0 = &As[1][0] + w * 512;
    short* const a1d1 = &As[1][0] + 2048 + w * 512;
    short* const b0d0 = &Bs[0][0] + w * 512;
    short* const b0d1 = &Bs[0][0] + 2048 + w * 512;
    short* const b1d0 = &Bs[1][0] + w * 512;
    short* const b1d1 = &Bs[1][0] + 2048 + w * 512;

    f32x4 acc[4][4];
#pragma unroll
    for (int m = 0; m < 4; ++m)
#pragma unroll
        for (int n = 0; n < 4; ++n)
            acc[m][n] = (f32x4){0.f, 0.f, 0.f, 0.f};

    const int slot = fg ^ ((fr >> 1) & 3);     // measured 0-conflict formula
    const int arow0 = wr * 64 + fr;
    const int brow0 = wc * 64 + fr;
    const int nk = Kd / 64;

    for (int kt = 0; kt < nk; ++kt) {
        gl2lds16(ag0, a0d0);       gl2lds16(ag0 + 32, a1d0);
        gl2lds16(ag1, a0d1);       gl2lds16(ag1 + 32, a1d1);
        gl2lds16(bg0, b0d0);       gl2lds16(bg0 + 32, b1d0);
        gl2lds16(bg1, b0d1);       gl2lds16(bg1 + 32, b1d1);
        ag0 += 64; ag1 += 64; bg0 += 64; bg1 += 64;
        __syncthreads();

#pragma unroll
        for (int s = 0; s < 2; ++s) {
            bf16x8 a[4], b[4];
#pragma unroll
            for (int m = 0; m < 4; ++m)
                a[m] = *(const bf16x8*)(&As[s][0] + (arow0 + m * 16) * 32 + slot * 8);
#pragma unroll
            for (int n = 0; n < 4; ++n)
                b[n] = *(const bf16x8*)(&Bs[s][0] + (brow0 + n * 16) * 32 + slot * 8);
#pragma unroll
            for (int m = 0; m < 4; ++m)
#pragma unroll
                for (int n = 0; n < 4; ++n)
                    acc[m][n] = __builtin_amdgcn_mfma_f32_16x16x32_bf16(a[m], b[n], acc[m][n], 0, 0, 0);
        }
        __syncthreads();
    }

    // ---- epilogue. C/D layout: col=lane&15, row=(lane>>4)*4+i. n-innermost. ----
    const int mrow0 = rb * 128 + wr * 64;
    const int col0 = cb * 128 + wc * 64;

    if (FC == 1) {
        const float* bp = sh ? biasS : biasM + (long long)z * FDIM;
        const float* gp = sh ? gateS : gateM + (long long)z * FDIM;
        unsigned short* outp = sh ? outS : outM;
        const long long obase = sh ? 0 : (long long)oE;
        float bv[4], gv[4]; int coln[4];
#pragma unroll
        for (int n = 0; n < 4; ++n) {
            coln[n] = col0 + n * 16 + fr;
            bv[n] = bp[coln[n]];
            gv[n] = gp[coln[n]];
        }
#pragma unroll
        for (int m = 0; m < 4; ++m) {
#pragma unroll
            for (int i = 0; i < 4; ++i) {
                int grow = mrow0 + m * 16 + fg * 4 + i;
                if (grow < M) {
                    unsigned short* rowp = outp + (obase + grow) * (long long)Ncols;
#pragma unroll
                    for (int n = 0; n < 4; ++n) {
                        float v = (acc[m][n][i] + bv[n]) * gv[n];
                        rowp[coln[n]] = f2bf(gelu_fast(v));
                    }
                }
            }
        }
    } else {
        float bv[4]; int coln[4];
        const float* bp = sh ? biasS : biasM + (long long)z * DDIM;
#pragma unroll
        for (int n = 0; n < 4; ++n) {
            coln[n] = col0 + n * 16 + fr;
            bv[n] = bp[coln[n]];
        }
        if (sh) {
            float sigw = 1.f / (1.f + expf(-swp[0]));
#pragma unroll
            for (int m = 0; m < 4; ++m) {
#pragma unroll
                for (int i = 0; i < 4; ++i) {
                    int grow = mrow0 + m * 16 + fg * 4 + i;
                    if (grow < M) {
                        unsigned short* rowp = outS + (long long)grow * DDIM;
#pragma unroll
                        for (int n = 0; n < 4; ++n)
                            rowp[coln[n]] = f2bf((acc[m][n][i] + bv[n]) * sigw);
                    }
                }
            }
        } else {
#pragma unroll
            for (int m = 0; m < 4; ++m) {
#pragma unroll
                for (int i = 0; i < 4; ++i) {
                    int grow = mrow0 + m * 16 + fg * 4 + i;
                    if (grow < M) {
                        int p = oE + grow;
                        float wv = roww[p];
                        unsigned short* rowp = outM + (long long)p * DDIM;   // compact
#pragma unroll
                        for (int n = 0; n < 4; ++n)
                            rowp[coln[n]] = f2bf((acc[m][n][i] + bv[n]) * wv);
                    }
                }
            }
        }
    }
}

// ------- final: y = ycomp[pos0]+ycomp[pos1]+ysh ; LayerNorm over D -------
__global__ void k_ln(const unsigned short* __restrict__ yc,
                     const unsigned short* __restrict__ ysh,
                     const int* __restrict__ pos,
                     const float* __restrict__ g, const float* __restrict__ b,
                     float* __restrict__ out) {
    const int wid = threadIdx.x >> 6, lane = threadIdx.x & 63;
    const long long t = (long long)blockIdx.x * 4 + wid;
    const long long b0 = (long long)pos[2 * t] * DDIM;
    const long long b1 = (long long)pos[2 * t + 1] * DDIM;
    const long long bs = t * DDIM;
    float v[16];
    float s = 0.f, sq = 0.f;
#pragma unroll
    for (int j = 0; j < 2; ++j) {
        int c0 = (lane + 64 * j) * 8;
        uint4 a0 = *(const uint4*)(yc + b0 + c0);
        uint4 a1 = *(const uint4*)(yc + b1 + c0);
        uint4 a2 = *(const uint4*)(ysh + bs + c0);
        const unsigned* u0 = (const unsigned*)&a0;
        const unsigned* u1 = (const unsigned*)&a1;
        const unsigned* u2 = (const unsigned*)&a2;
#pragma unroll
        for (int qq = 0; qq < 4; ++qq) {
            float lo = bf2f((unsigned short)u0[qq]) + bf2f((unsigned short)u1[qq]) +
                       bf2f((unsigned short)u2[qq]);
            float hi = bf2f((unsigned short)(u0[qq] >> 16)) + bf2f((unsigned short)(u1[qq] >> 16)) +
                       bf2f((unsigned short)(u2[qq] >> 16));
            v[j * 8 + qq * 2] = lo;
            v[j * 8 + qq * 2 + 1] = hi;
            s += lo + hi;
            sq += lo * lo + hi * hi;
        }
    }
#pragma unroll
    for (int off = 32; off; off >>= 1) {
        s += __shfl_xor(s, off);
        sq += __shfl_xor(sq, off);
    }
    const float mean = s * (1.f / DDIM);
    const float var = sq * (1.f / DDIM) - mean * mean;
    const float inv = rsqrtf(var + 1e-5f);
#pragma unroll
    for (int j = 0; j < 2; ++j) {
        int c0 = (lane + 64 * j) * 8;
#pragma unroll
        for (int h = 0; h < 2; ++h) {
            float4 o4;
            float* op = (float*)&o4;
#pragma unroll
            for (int qq = 0; qq < 4; ++qq) {
                int k = h * 4 + qq;
                int col = c0 + k;
                op[qq] = (v[j * 8 + k] - mean) * inv * g[col] + b[col];
            }
            *(float4*)(out + bs + c0 + h * 4) = o4;
        }
    }
}

extern "C" void kernel_launch(void* const* d_in, const int* in_sizes, int n_in,
                              void* d_out, int out_size, void* d_ws, size_t ws_size,
                              hipStream_t stream) {
    const float* x    = (const float*)d_in[0];
    const float* rw   = (const float*)d_in[1];
    const float* rb   = (const float*)d_in[2];
    const float* w1   = (const float*)d_in[3];
    const float* b1   = (const float*)d_in[4];
    const float* gate = (const float*)d_in[5];
    const float* w2   = (const float*)d_in[6];
    const float* b2   = (const float*)d_in[7];
    const float* sw1  = (const float*)d_in[8];
    const float* sb1  = (const float*)d_in[9];
    const float* sgate= (const float*)d_in[10];
    const float* sw2  = (const float*)d_in[11];
    const float* sb2  = (const float*)d_in[12];
    const float* swt  = (const float*)d_in[13];
    const float* lng  = (const float*)d_in[14];
    const float* lnb  = (const float*)d_in[15];
    float* out = (float*)d_out;

    char* p = (char*)d_ws;
    auto take = [&](size_t n) { char* r = p; p += (n + 255) & ~(size_t)255; return r; };
    short* xb   = (short*)take((size_t)T_TOK * DDIM * 2);
    short* w1t  = (short*)take((size_t)NEXP * FDIM * DDIM * 2);
    short* w2t  = (short*)take((size_t)NEXP * DDIM * FDIM * 2);
    short* sw1t = (short*)take((size_t)F2DIM * DDIM * 2);
    short* sw2t = (short*)take((size_t)DDIM * F2DIM * 2);
    short* hbuf = (short*)take((size_t)2 * T_TOK * FDIM * 2);
    short* hs   = (short*)take((size_t)T_TOK * F2DIM * 2);
    unsigned short* ycomp = (unsigned short*)take((size_t)2 * T_TOK * DDIM * 2);
    unsigned short* ysh   = (unsigned short*)take((size_t)T_TOK * DDIM * 2);
    int* eid    = (int*)take((size_t)T_TOK * 2 * 4);
    float* ewt  = (float*)take((size_t)T_TOK * 2 * 4);
    int* rowtok = (int*)take((size_t)2 * T_TOK * 4);
    float* roww = (float*)take((size_t)2 * T_TOK * 4);
    int* pos    = (int*)take((size_t)2 * T_TOK * 4);
    int* cnt    = (int*)take(64);
    int* offs   = (int*)take(64);
    int* cursor = (int*)take(64);

    hipMemsetAsync(cnt, 0, NEXP * sizeof(int), stream);
    k_router<<<T_TOK / 4, 256, 0, stream>>>(x, rw, rb, eid, ewt, cnt, (unsigned short*)xb);
    k_scan<<<1, 64, 0, stream>>>(cnt, offs, cursor);
    k_scatter<<<T_TOK / 256, 256, 0, stream>>>(eid, ewt, cursor, rowtok, roww, pos);

    k_tpAll<<<34816, 256, 0, stream>>>(w1, w2, sw1, sw2,
                                       (unsigned short*)w1t, (unsigned short*)w2t,
                                       (unsigned short*)sw1t, (unsigned short*)sw2t);

    // fc1: tiles = sum_e ceil(cnt/128)*32 (<= 135*32=4320) + shared 64*16=1024
    k_fc<1><<<5344, 256, 0, stream>>>(
        xb, xb, w1t, sw1t, b1, sb1, gate, sgate,
        (unsigned short*)hbuf, (unsigned short*)hs, cnt, offs, rowtok, roww, swt);
    // fc2: tiles = sum_e ceil(cnt/128)*8 (<= 1080) + shared 64*8=512
    k_fc<2><<<1592, 256, 0, stream>>>(
        hbuf, hs, w2t, sw2t, b2, sb2, (const float*)nullptr, (const float*)nullptr,
        ycomp, ysh, cnt, offs, rowtok, roww, swt);

    k_ln<<<T_TOK / 4, 256, 0, stream>>>(ycomp, ysh, pos, lng, lnb, out);
}